// Round 13
// baseline (187.241 us; speedup 1.0000x reference)
//
#include <hip/hip_runtime.h>

typedef unsigned short u16;
typedef short bf16x8 __attribute__((ext_vector_type(8)));
typedef u16 u16x8 __attribute__((ext_vector_type(8)));
typedef float f32x4 __attribute__((ext_vector_type(4)));

#define K_DIM 256
#define L_DIM 4096
#define NBATCH 4

static __device__ __forceinline__ u16 f2bf(float f) {
    unsigned u = __float_as_uint(f);
    unsigned r = (u + 0x7FFFu + ((u >> 16) & 1u)) >> 16;
    return (u16)r;
}
static __device__ __forceinline__ float bf2f(u16 v) {
    return __uint_as_float(((unsigned)v) << 16);
}

#define GLOAD16(g, l) __builtin_amdgcn_global_load_lds( \
    (const __attribute__((address_space(1))) void*)(g), \
    (__attribute__((address_space(3))) void*)(l), 16, 0, 0)

// ---------------------------------------------------------------------------
// K1: depthwise 3x3 conv + transpose + bf16 cast; weight casts folded in.
// [R12 verbatim]
// ---------------------------------------------------------------------------
__global__ __launch_bounds__(256) void prep_kernel(
    const float* __restrict__ x, const float* __restrict__ dw_w,
    const float* __restrict__ dw_b, const float* __restrict__ pin_w,
    const float* __restrict__ pw_w, const float* __restrict__ pout_w,
    u16* __restrict__ xb_t, u16* __restrict__ dwc_t,
    u16* __restrict__ pin_wb, u16* __restrict__ pw_wb,
    u16* __restrict__ pout_wb)
{
    if (blockIdx.x == 4) {                      // weight-cast blocks
        if (blockIdx.z != 0) return;
        const int end = (blockIdx.y + 1) * 2560;
        for (int k = blockIdx.y * 2560 + threadIdx.x; k < end; k += 256) {
            if (k < 65536) pin_wb[k] = f2bf(pin_w[k]);
            else if (k < 98304) {
                int j = k - 65536;
                pw_wb[j] = ((j >> 8) < 112) ? f2bf(pw_w[j]) : (u16)0;
            } else {
                int j = k - 98304;
                pout_wb[j] = f2bf(pout_w[j]);
            }
        }
        return;
    }

    __shared__ u16 tx_[64][66];
    __shared__ u16 td_[64][66];
    const int c0 = blockIdx.x * 64, h = blockIdx.y, n = blockIdx.z;
    const int t = threadIdx.x;
    const float* xn = x + (size_t)n * 256 * L_DIM;

    const int w4 = (t & 15) * 4;          // 0..60
    const int cs = t >> 4;                // 0..15

    #pragma unroll
    for (int j = 0; j < 4; ++j) {
        const int cl = cs * 4 + j, c = c0 + cl;
        const float* xc = xn + (size_t)c * L_DIM;
        const float* w9 = dw_w + c * 9;

        float s[4];
        const float bv = dw_b[c];
        #pragma unroll
        for (int k = 0; k < 4; ++k) s[k] = bv;
        f32x4 center;

        #pragma unroll
        for (int dy = 0; dy < 3; ++dy) {
            const int hh = h + dy - 1;
            if (hh < 0 || hh > 63) continue;        // block-uniform
            const float* row = xc + hh * 64;
            const f32x4 m = *(const f32x4*)(row + w4);
            const float flv = row[(w4 > 0) ? w4 - 1 : 0];
            const float frv = row[(w4 + 4 < 64) ? w4 + 4 : 63];
            if (dy == 1) center = m;
            #pragma unroll
            for (int k = 0; k < 4; ++k) {
                const int w = w4 + k;
                const float lv = (w > 0) ? 1.f : 0.f;
                const float rv = (w < 63) ? 1.f : 0.f;
                const float xm = (k == 0) ? flv : m[k - 1];
                const float xp = (k == 3) ? frv : m[k + 1];
                s[k] = fmaf(xm * lv, w9[dy*3 + 0], s[k]);
                s[k] = fmaf(m[k],    w9[dy*3 + 1], s[k]);
                s[k] = fmaf(xp * rv, w9[dy*3 + 2], s[k]);
            }
        }
        #pragma unroll
        for (int k = 0; k < 4; ++k) {
            tx_[w4 + k][cl] = f2bf(center[k]);
            td_[w4 + k][cl] = f2bf(s[k]);
        }
    }
    __syncthreads();

    const int cc = t & 63, cq = t >> 6;
    for (int j = 0; j < 16; ++j) {
        const int wl = j * 4 + cq;
        const size_t o = ((size_t)n * L_DIM + h * 64 + wl) * 256 + c0 + cc;
        xb_t[o]  = tx_[wl][cc];
        dwc_t[o] = td_[wl][cc];
    }
}

// ---------------------------------------------------------------------------
// K2: pin + pw GEMMs in one dispatch.   [R12 verbatim]
// ---------------------------------------------------------------------------
__global__ __launch_bounds__(256) void gemm_dual(
    const u16* __restrict__ xb_t, const u16* __restrict__ dwc_t,
    const u16* __restrict__ pin_wb, const u16* __restrict__ pw_wb,
    const float* __restrict__ pin_b, const float* __restrict__ pw_b,
    u16* __restrict__ val_b, float* __restrict__ omb)
{
    __shared__ u16 lds[16384];
    const int bx = blockIdx.x;
    const bool isPw = (bx == 2);
    const u16* Ag = isPw ? dwc_t : xb_t;
    const u16* Bg = isPw ? pw_wb : pin_wb;
    const float* bias = isPw ? pw_b : pin_b;
    const int n0 = isPw ? 0 : bx * 128;
    const int Ncols = isPw ? 112 : 256;
    const int ldC = isPw ? 112 : 256;
    const int m0 = blockIdx.y * 128;

    const int t = threadIdx.x;
    const int wave = t >> 6, lane = t & 63;
    const int lr = lane & 15, lk = lane >> 4;
    const int wr = wave >> 1, wc = wave & 1;
    const int wbase = wave << 10;

    const int srow = t >> 2;
    const int scol = (t & 3) * 8;
    const u16* ga0 = Ag + (size_t)(m0 + srow)      * K_DIM + scol;
    const u16* ga1 = Ag + (size_t)(m0 + 64 + srow) * K_DIM + scol;
    const u16* gb0 = Bg + (size_t)(n0 + srow)      * K_DIM + scol;
    const u16* gb1 = Bg + (size_t)(n0 + 64 + srow) * K_DIM + scol;

    f32x4 acc[4][4];
    #pragma unroll
    for (int m = 0; m < 4; ++m)
        #pragma unroll
        for (int n = 0; n < 4; ++n) acc[m][n] = (f32x4){0.f, 0.f, 0.f, 0.f};

    auto stage = [&](int b, int kt) {
        const int ko = kt * 32;
        char* base = (char*)lds + b * 16384 + wbase;
        GLOAD16(ga0 + ko, base);
        GLOAD16(ga1 + ko, base + 4096);
        GLOAD16(gb0 + ko, base + 8192);
        GLOAD16(gb1 + ko, base + 12288);
    };

    stage(0, 0);
    asm volatile("s_waitcnt vmcnt(0)" ::: "memory");
    __syncthreads();

    for (int kt = 0; kt < 8; ++kt) {
        const int cur = kt & 1;
        if (kt < 7) stage(cur ^ 1, kt + 1);
        const char* la = (const char*)lds + cur * 16384;
        const char* lb = la + 8192;
        bf16x8 af[4], bfr[4];
        #pragma unroll
        for (int m = 0; m < 4; ++m)
            af[m] = *(const bf16x8*)(la + ((wr*64 + m*16 + lr) * 32 + lk * 8) * 2);
        #pragma unroll
        for (int n = 0; n < 4; ++n)
            bfr[n] = *(const bf16x8*)(lb + ((wc*64 + n*16 + lr) * 32 + lk * 8) * 2);
        #pragma unroll
        for (int m = 0; m < 4; ++m)
            #pragma unroll
            for (int n = 0; n < 4; ++n)
                acc[m][n] = __builtin_amdgcn_mfma_f32_16x16x32_bf16(
                    af[m], bfr[n], acc[m][n], 0, 0, 0);
        asm volatile("s_waitcnt vmcnt(0)" ::: "memory");
        __syncthreads();
    }

    #pragma unroll
    for (int m = 0; m < 4; ++m) {
        #pragma unroll
        for (int n = 0; n < 4; ++n) {
            const int col = n0 + wc*64 + n*16 + lr;
            if (col < Ncols) {
                const float bv = bias[col];
                #pragma unroll
                for (int r = 0; r < 4; ++r) {
                    const int row = m0 + wr*64 + m*16 + lk*4 + r;
                    const float o = acc[m][n][r] + bv;
                    const size_t off = (size_t)row * ldC + col;
                    if (isPw) omb[off] = o;
                    else      val_b[off] = f2bf(o);
                }
            }
        }
    }
}

// ---------------------------------------------------------------------------
// K3: fused deformable gather + output projection.
// CHANGE vs R12: Phase A explicitly software-pipelined.  Per p: issue
// slot1(p) loads -> FMA slot0(p) -> issue slot0(p+1) loads -> FMA slot1(p).
// 8 u16x8 loads stay in flight in named SSA variables (forces the register
// allocator to batch; R11 showed VGPR=40 i.e. serialized loads).  Per-
// accumulator fma order (p asc, corner asc) unchanged -> bitwise-identical.
// ---------------------------------------------------------------------------
__global__ __launch_bounds__(512, 4) void gather_pout(
    const float* __restrict__ om, const u16* __restrict__ val,
    const u16* __restrict__ pout_wb, const float* __restrict__ pout_b,
    float* __restrict__ out)
{
    __shared__ u16 sacc[32][264];
    __shared__ float som[4096];                // 16 KB (14 KB used)
    const int blk = blockIdx.x;                // 0..511
    const int xcd = blk & 7, s = blk >> 3;     // s: 0..63
    const int half = s & 1, rd = (s >> 1) & 7, n = s >> 4;
    const int h = xcd * 8 + rd;
    const int l0 = h * 64 + half * 32;
    const int t = threadIdx.x;

    // stage om slice: 2 x (512 thr x 16 B); wave-uniform LDS base + lane*16
    {
        const float* omsrc = om + ((size_t)n * L_DIM + l0) * 112;
        const int wb = (t >> 6) << 10;         // wave byte base
        GLOAD16(omsrc + t * 4,        (char*)som + wb);
        GLOAD16(omsrc + 2048 + t * 4, (char*)som + 8192 + wb);
        asm volatile("s_waitcnt vmcnt(0)" ::: "memory");
        __syncthreads();
    }

    // ---- Phase A: pipelined deformable bilinear gather -> sacc ----
    {
        const u16* valn = val + (size_t)n * L_DIM * 256;
        const float ybase = (float)h - 1.f;

        const int pos0 = t >> 5;               // 0..15
        const int pos1 = pos0 + 16;            // 16..31
        const int g = (t >> 3) & 3;
        const int ch = (t & 7) * 8;
        const float* omp0 = som + pos0 * 112 + g * 27;
        const float* omp1 = som + pos1 * 112 + g * 27;
        const u16* vb = valn + g * 64 + ch;
        const float xb0 = (float)((l0 + pos0) & 63) - 1.f;
        const float xb1 = (float)((l0 + pos1) & 63) - 1.f;

        // address + weight calc, arithmetic identical to R12
        auto calc = [&](const float* omp, float xb, int p,
                        const u16** addr, float* w) {
            const float py = (ybase + (float)(p / 3)) + omp[p*3 + 1];
            const float px = xb + (float)(p % 3) + omp[p*3 + 0];
            const float mk = omp[p*3 + 2];
            const float y0 = floorf(py), x0 = floorf(px);
            const float fy = py - y0, fx = px - x0;
            const int iy0 = (int)y0, ix0 = (int)x0;
            const float wy[2] = {mk * (1.f - fy), mk * fy};
            const float wx[2] = {1.f - fx, fx};
            #pragma unroll
            for (int c4 = 0; c4 < 4; ++c4) {
                const int dy = c4 >> 1, dx = c4 & 1;
                const int iy = iy0 + dy, ix = ix0 + dx;
                const bool ok = ((unsigned)iy < 64u) & ((unsigned)ix < 64u);
                w[c4] = ok ? wy[dy] * wx[dx] : 0.f;
                const int iyc = min(max(iy, 0), 63);
                const int ixc = min(max(ix, 0), 63);
                addr[c4] = vb + (size_t)(iyc * 64 + ixc) * 256;
            }
        };

        float a0[8], a1[8];
        #pragma unroll
        for (int j = 0; j < 8; ++j) { a0[j] = 0.f; a1[j] = 0.f; }

        u16x8 v0[4], v1[4];
        float w0[4], w1[4];
        {   // prologue: slot0 p=0 loads in flight
            const u16* ap[4];
            calc(omp0, xb0, 0, ap, w0);
            #pragma unroll
            for (int c = 0; c < 4; ++c) v0[c] = *(const u16x8*)ap[c];
        }

        #pragma unroll
        for (int p = 0; p < 9; ++p) {
            // issue slot1(p) loads
            {
                const u16* ap[4];
                calc(omp1, xb1, p, ap, w1);
                #pragma unroll
                for (int c = 0; c < 4; ++c) v1[c] = *(const u16x8*)ap[c];
            }
            // consume slot0(p)
            #pragma unroll
            for (int c = 0; c < 4; ++c)
                #pragma unroll
                for (int j = 0; j < 8; ++j)
                    a0[j] = fmaf(w0[c], bf2f(v0[c][j]), a0[j]);
            // issue slot0(p+1) loads
            if (p < 8) {
                const u16* ap[4];
                float nw[4];
                calc(omp0, xb0, p + 1, ap, nw);
                u16x8 nv[4];
                #pragma unroll
                for (int c = 0; c < 4; ++c) nv[c] = *(const u16x8*)ap[c];
                // consume slot1(p)
                #pragma unroll
                for (int c = 0; c < 4; ++c)
                    #pragma unroll
                    for (int j = 0; j < 8; ++j)
                        a1[j] = fmaf(w1[c], bf2f(v1[c][j]), a1[j]);
                #pragma unroll
                for (int c = 0; c < 4; ++c) { v0[c] = nv[c]; w0[c] = nw[c]; }
            } else {
                #pragma unroll
                for (int c = 0; c < 4; ++c)
                    #pragma unroll
                    for (int j = 0; j < 8; ++j)
                        a1[j] = fmaf(w1[c], bf2f(v1[c][j]), a1[j]);
            }
        }

        u16x8 o0, o1;
        #pragma unroll
        for (int j = 0; j < 8; ++j) { o0[j] = f2bf(a0[j]); o1[j] = f2bf(a1[j]); }
        *(u16x8*)(&sacc[pos0][g*64 + ch]) = o0;
        *(u16x8*)(&sacc[pos1][g*64 + ch]) = o1;
    }
    __syncthreads();

    // ---- Phase B: pout GEMM. Wave owns c-rows [wave*32, wave*32+32) x 32 cols ----
    const int wave = t >> 6, lane = t & 63;
    const int lr = lane & 15, lk = lane >> 4;

    f32x4 acc4[2][2];
    #pragma unroll
    for (int m = 0; m < 2; ++m)
        #pragma unroll
        for (int nn = 0; nn < 2; ++nn) acc4[m][nn] = (f32x4){0.f, 0.f, 0.f, 0.f};

    #pragma unroll
    for (int kt = 0; kt < 8; ++kt) {
        bf16x8 bfr[2];
        #pragma unroll
        for (int nn = 0; nn < 2; ++nn)
            bfr[nn] = *(const bf16x8*)(&sacc[nn*16 + lr][kt*32 + lk*8]);
        #pragma unroll
        for (int m = 0; m < 2; ++m) {
            const bf16x8 af = *(const bf16x8*)(pout_wb +
                (size_t)(wave*32 + m*16 + lr) * K_DIM + kt*32 + lk*8);
            #pragma unroll
            for (int nn = 0; nn < 2; ++nn)
                acc4[m][nn] = __builtin_amdgcn_mfma_f32_16x16x32_bf16(
                    af, bfr[nn], acc4[m][nn], 0, 0, 0);
        }
    }

    float* outn = out + (size_t)n * 256 * L_DIM;
    #pragma unroll
    for (int m = 0; m < 2; ++m) {
        #pragma unroll
        for (int nn = 0; nn < 2; ++nn) {
            const int col = l0 + nn*16 + lr;
            #pragma unroll
            for (int r = 0; r < 4; ++r) {
                const int row = wave*32 + m*16 + lk*4 + r;
                outn[(size_t)row * L_DIM + col] = acc4[m][nn][r] + pout_b[row];
            }
        }
    }
}

// ---------------------------------------------------------------------------
extern "C" void kernel_launch(void* const* d_in, const int* in_sizes, int n_in,
                              void* d_out, int out_size, void* d_ws, size_t ws_size,
                              hipStream_t stream) {
    const float* x      = (const float*)d_in[0];
    const float* dw_w   = (const float*)d_in[1];
    const float* dw_b   = (const float*)d_in[2];
    const float* pw_w   = (const float*)d_in[3];
    const float* pw_b   = (const float*)d_in[4];
    const float* pin_w  = (const float*)d_in[5];
    const float* pin_b  = (const float*)d_in[6];
    const float* pout_w = (const float*)d_in[7];
    const float* pout_b = (const float*)d_in[8];
    float* out = (float*)d_out;

    char* ws = (char*)d_ws;
    u16*   xb_t    = (u16*)ws;                      //  8,388,608
    u16*   dwc_t   = (u16*)(ws + 8388608);          //  8,388,608
    u16*   val_b   = (u16*)(ws + 16777216);         //  8,388,608
    float* omb     = (float*)(ws + 25165824);       //  7,340,032
    u16*   pin_wb  = (u16*)(ws + 32505856);         //    131,072
    u16*   pw_wb   = (u16*)(ws + 32636928);         //     65,536 (128 rows)
    u16*   pout_wb = (u16*)(ws + 32702464);         //    131,072

    // K1: depthwise conv + transpose-cast + weight casts
    prep_kernel<<<dim3(5, 64, NBATCH), 256, 0, stream>>>(
        x, dw_w, dw_b, pin_w, pw_w, pout_w,
        xb_t, dwc_t, pin_wb, pw_wb, pout_wb);

    // K2: val = pin(x) [bf16], om = pw(dwc) [fp32]
    gemm_dual<<<dim3(3, 128), 256, 0, stream>>>(
        xb_t, dwc_t, pin_wb, pw_wb, pin_b, pw_b, val_b, omb);

    // K3: deformable gather (software-pipelined loads) + pout projection
    gather_pout<<<dim3(512), 512, 0, stream>>>(
        omb, val_b, pout_wb, pout_b, out);
}

// Round 14
// 58.632 us; speedup vs baseline: 3.1935x; 3.1935x over previous
//
#include <hip/hip_runtime.h>

typedef unsigned short u16;
typedef short bf16x8 __attribute__((ext_vector_type(8)));
typedef u16 u16x8 __attribute__((ext_vector_type(8)));
typedef float f32x4 __attribute__((ext_vector_type(4)));

#define K_DIM 256
#define L_DIM 4096
#define NBATCH 4

static __device__ __forceinline__ u16 f2bf(float f) {
    unsigned u = __float_as_uint(f);
    unsigned r = (u + 0x7FFFu + ((u >> 16) & 1u)) >> 16;
    return (u16)r;
}
static __device__ __forceinline__ float bf2f(u16 v) {
    return __uint_as_float(((unsigned)v) << 16);
}

#define GLOAD16(g, l) __builtin_amdgcn_global_load_lds( \
    (const __attribute__((address_space(1))) void*)(g), \
    (__attribute__((address_space(3))) void*)(l), 16, 0, 0)

// ---------------------------------------------------------------------------
// K1: depthwise 3x3 conv + transpose + bf16 cast; weight casts folded in.
// [R12 verbatim]
// ---------------------------------------------------------------------------
__global__ __launch_bounds__(256) void prep_kernel(
    const float* __restrict__ x, const float* __restrict__ dw_w,
    const float* __restrict__ dw_b, const float* __restrict__ pin_w,
    const float* __restrict__ pw_w, const float* __restrict__ pout_w,
    u16* __restrict__ xb_t, u16* __restrict__ dwc_t,
    u16* __restrict__ pin_wb, u16* __restrict__ pw_wb,
    u16* __restrict__ pout_wb)
{
    if (blockIdx.x == 4) {                      // weight-cast blocks
        if (blockIdx.z != 0) return;
        const int end = (blockIdx.y + 1) * 2560;
        for (int k = blockIdx.y * 2560 + threadIdx.x; k < end; k += 256) {
            if (k < 65536) pin_wb[k] = f2bf(pin_w[k]);
            else if (k < 98304) {
                int j = k - 65536;
                pw_wb[j] = ((j >> 8) < 112) ? f2bf(pw_w[j]) : (u16)0;
            } else {
                int j = k - 98304;
                pout_wb[j] = f2bf(pout_w[j]);
            }
        }
        return;
    }

    __shared__ u16 tx_[64][66];
    __shared__ u16 td_[64][66];
    const int c0 = blockIdx.x * 64, h = blockIdx.y, n = blockIdx.z;
    const int t = threadIdx.x;
    const float* xn = x + (size_t)n * 256 * L_DIM;

    const int w4 = (t & 15) * 4;          // 0..60
    const int cs = t >> 4;                // 0..15

    #pragma unroll
    for (int j = 0; j < 4; ++j) {
        const int cl = cs * 4 + j, c = c0 + cl;
        const float* xc = xn + (size_t)c * L_DIM;
        const float* w9 = dw_w + c * 9;

        float s[4];
        const float bv = dw_b[c];
        #pragma unroll
        for (int k = 0; k < 4; ++k) s[k] = bv;
        f32x4 center;

        #pragma unroll
        for (int dy = 0; dy < 3; ++dy) {
            const int hh = h + dy - 1;
            if (hh < 0 || hh > 63) continue;        // block-uniform
            const float* row = xc + hh * 64;
            const f32x4 m = *(const f32x4*)(row + w4);
            const float flv = row[(w4 > 0) ? w4 - 1 : 0];
            const float frv = row[(w4 + 4 < 64) ? w4 + 4 : 63];
            if (dy == 1) center = m;
            #pragma unroll
            for (int k = 0; k < 4; ++k) {
                const int w = w4 + k;
                const float lv = (w > 0) ? 1.f : 0.f;
                const float rv = (w < 63) ? 1.f : 0.f;
                const float xm = (k == 0) ? flv : m[k - 1];
                const float xp = (k == 3) ? frv : m[k + 1];
                s[k] = fmaf(xm * lv, w9[dy*3 + 0], s[k]);
                s[k] = fmaf(m[k],    w9[dy*3 + 1], s[k]);
                s[k] = fmaf(xp * rv, w9[dy*3 + 2], s[k]);
            }
        }
        #pragma unroll
        for (int k = 0; k < 4; ++k) {
            tx_[w4 + k][cl] = f2bf(center[k]);
            td_[w4 + k][cl] = f2bf(s[k]);
        }
    }
    __syncthreads();

    const int cc = t & 63, cq = t >> 6;
    for (int j = 0; j < 16; ++j) {
        const int wl = j * 4 + cq;
        const size_t o = ((size_t)n * L_DIM + h * 64 + wl) * 256 + c0 + cc;
        xb_t[o]  = tx_[wl][cc];
        dwc_t[o] = td_[wl][cc];
    }
}

// ---------------------------------------------------------------------------
// K2: pin + pw GEMMs in one dispatch.   [R12 verbatim]
// ---------------------------------------------------------------------------
__global__ __launch_bounds__(256) void gemm_dual(
    const u16* __restrict__ xb_t, const u16* __restrict__ dwc_t,
    const u16* __restrict__ pin_wb, const u16* __restrict__ pw_wb,
    const float* __restrict__ pin_b, const float* __restrict__ pw_b,
    u16* __restrict__ val_b, float* __restrict__ omb)
{
    __shared__ u16 lds[16384];
    const int bx = blockIdx.x;
    const bool isPw = (bx == 2);
    const u16* Ag = isPw ? dwc_t : xb_t;
    const u16* Bg = isPw ? pw_wb : pin_wb;
    const float* bias = isPw ? pw_b : pin_b;
    const int n0 = isPw ? 0 : bx * 128;
    const int Ncols = isPw ? 112 : 256;
    const int ldC = isPw ? 112 : 256;
    const int m0 = blockIdx.y * 128;

    const int t = threadIdx.x;
    const int wave = t >> 6, lane = t & 63;
    const int lr = lane & 15, lk = lane >> 4;
    const int wr = wave >> 1, wc = wave & 1;
    const int wbase = wave << 10;

    const int srow = t >> 2;
    const int scol = (t & 3) * 8;
    const u16* ga0 = Ag + (size_t)(m0 + srow)      * K_DIM + scol;
    const u16* ga1 = Ag + (size_t)(m0 + 64 + srow) * K_DIM + scol;
    const u16* gb0 = Bg + (size_t)(n0 + srow)      * K_DIM + scol;
    const u16* gb1 = Bg + (size_t)(n0 + 64 + srow) * K_DIM + scol;

    f32x4 acc[4][4];
    #pragma unroll
    for (int m = 0; m < 4; ++m)
        #pragma unroll
        for (int n = 0; n < 4; ++n) acc[m][n] = (f32x4){0.f, 0.f, 0.f, 0.f};

    auto stage = [&](int b, int kt) {
        const int ko = kt * 32;
        char* base = (char*)lds + b * 16384 + wbase;
        GLOAD16(ga0 + ko, base);
        GLOAD16(ga1 + ko, base + 4096);
        GLOAD16(gb0 + ko, base + 8192);
        GLOAD16(gb1 + ko, base + 12288);
    };

    stage(0, 0);
    asm volatile("s_waitcnt vmcnt(0)" ::: "memory");
    __syncthreads();

    for (int kt = 0; kt < 8; ++kt) {
        const int cur = kt & 1;
        if (kt < 7) stage(cur ^ 1, kt + 1);
        const char* la = (const char*)lds + cur * 16384;
        const char* lb = la + 8192;
        bf16x8 af[4], bfr[4];
        #pragma unroll
        for (int m = 0; m < 4; ++m)
            af[m] = *(const bf16x8*)(la + ((wr*64 + m*16 + lr) * 32 + lk * 8) * 2);
        #pragma unroll
        for (int n = 0; n < 4; ++n)
            bfr[n] = *(const bf16x8*)(lb + ((wc*64 + n*16 + lr) * 32 + lk * 8) * 2);
        #pragma unroll
        for (int m = 0; m < 4; ++m)
            #pragma unroll
            for (int n = 0; n < 4; ++n)
                acc[m][n] = __builtin_amdgcn_mfma_f32_16x16x32_bf16(
                    af[m], bfr[n], acc[m][n], 0, 0, 0);
        asm volatile("s_waitcnt vmcnt(0)" ::: "memory");
        __syncthreads();
    }

    #pragma unroll
    for (int m = 0; m < 4; ++m) {
        #pragma unroll
        for (int n = 0; n < 4; ++n) {
            const int col = n0 + wc*64 + n*16 + lr;
            if (col < Ncols) {
                const float bv = bias[col];
                #pragma unroll
                for (int r = 0; r < 4; ++r) {
                    const int row = m0 + wr*64 + m*16 + lk*4 + r;
                    const float o = acc[m][n][r] + bv;
                    const size_t off = (size_t)row * ldC + col;
                    if (isPw) omb[off] = o;
                    else      val_b[off] = f2bf(o);
                }
            }
        }
    }
}

// ---------------------------------------------------------------------------
// K3a: deformable bilinear gather, max-occupancy version.
// 2048 blocks x 256 thr, __launch_bounds__(256,8) -> target 32 waves/CU
// (2x the fused version).  Block = 8 positions; thread = 1 slot (pos,g,8ch).
// om slice (8 x 112 = 3.6 KB) LDS-staged.  Straight-line R12 loop body
// (no lambdas/arrays across control flow - R13's scratch-spill lesson).
// XCD decode: each XCD gets 2048 contiguous positions (~1.1 MB val slice).
// acc writes: 256 thr x 16 B = 4 KB fully contiguous per block.
// ---------------------------------------------------------------------------
__global__ __launch_bounds__(256, 8) void gather_kernel(
    const float* __restrict__ om, const u16* __restrict__ val,
    u16* __restrict__ accb)
{
    __shared__ float som[904];                 // 8*112 floats + pad
    const int blk = blockIdx.x;                // 0..2047
    const int grp = (blk & 7) * 256 + (blk >> 3);   // pos-group 0..2047
    const int n = grp >> 9;                    // 512 groups per n
    const int l0 = (grp & 511) * 8;            // 8-pos base within n
    const int t = threadIdx.x;

    // stage om slice (3584 B): waves 0-2 full, wave 3 lanes 0-31
    {
        const float* omsrc = om + ((size_t)n * L_DIM + l0) * 112;
        if (t < 224) {
            const int wb = (t >> 6) << 10;     // wave-uniform byte base
            GLOAD16(omsrc + t * 4, (char*)som + wb);
        }
        asm volatile("s_waitcnt vmcnt(0)" ::: "memory");
        __syncthreads();
    }

    const int pos = t >> 5;                    // 0..7
    const int g = (t >> 3) & 3;
    const int ch = (t & 7) * 8;
    const int l = l0 + pos;
    const float* omp = som + pos * 112 + g * 27;
    const u16* vb = val + (size_t)n * L_DIM * 256 + g * 64 + ch;
    const float ybase = (float)(l >> 6) - 1.f;
    const float xb = (float)(l & 63) - 1.f;

    float a[8];
    #pragma unroll
    for (int j = 0; j < 8; ++j) a[j] = 0.f;

    #pragma unroll 3
    for (int p = 0; p < 9; ++p) {
        const float ox = omp[p*3 + 0];
        const float oy = omp[p*3 + 1];
        const float mk = omp[p*3 + 2];
        const float py = ybase + (float)(p / 3) + oy;
        const float px = xb + (float)(p % 3) + ox;
        const float y0 = floorf(py), x0 = floorf(px);
        const float fy = py - y0, fx = px - x0;
        const int iy0 = (int)y0, ix0 = (int)x0;
        const float wy[2] = {mk * (1.f - fy), mk * fy};
        const float wx[2] = {1.f - fx, fx};
        #pragma unroll
        for (int c4 = 0; c4 < 4; ++c4) {
            const int dy = c4 >> 1, dx = c4 & 1;
            const int iy = iy0 + dy, ix = ix0 + dx;
            const bool ok = ((unsigned)iy < 64u) & ((unsigned)ix < 64u);
            const float wgt = ok ? wy[dy] * wx[dx] : 0.f;
            const int iyc = min(max(iy, 0), 63);
            const int ixc = min(max(ix, 0), 63);
            const u16x8 v = *(const u16x8*)(vb + (size_t)(iyc * 64 + ixc) * 256);
            #pragma unroll
            for (int j = 0; j < 8; ++j) a[j] = fmaf(wgt, bf2f(v[j]), a[j]);
        }
    }
    u16x8 o;
    #pragma unroll
    for (int j = 0; j < 8; ++j) o[j] = f2bf(a[j]);
    *(u16x8*)(accb + ((size_t)n * L_DIM + l) * 256 + g * 64 + ch) = o;
}

// ---------------------------------------------------------------------------
// K3b: pout GEMM.  out[n][c][l] = sum_k pout_w[c,k]*acc[n*L+l,k] + pout_b[c].
// A = pout_wb [256,256] bf16, B = acc rows, 128x128 tile, transposed fp32
// store.  Grid (32, 2, NBATCH).  [R2-proven structure]
// ---------------------------------------------------------------------------
__global__ __launch_bounds__(256) void gemm_pout(
    const u16* __restrict__ accb, const u16* __restrict__ pout_wb,
    const float* __restrict__ pout_b, float* __restrict__ out)
{
    __shared__ u16 lds[16384];
    const int z = blockIdx.z;
    const u16* Bg = accb + (size_t)z * L_DIM * 256;
    const int n0 = blockIdx.x * 128;           // l tile
    const int m0 = blockIdx.y * 128;           // c tile

    const int t = threadIdx.x;
    const int wave = t >> 6, lane = t & 63;
    const int lr = lane & 15, lk = lane >> 4;
    const int wr = wave >> 1, wc = wave & 1;
    const int wbase = wave << 10;

    const int srow = t >> 2;
    const int scol = (t & 3) * 8;
    const u16* ga0 = pout_wb + (size_t)(m0 + srow)      * K_DIM + scol;
    const u16* ga1 = pout_wb + (size_t)(m0 + 64 + srow) * K_DIM + scol;
    const u16* gb0 = Bg + (size_t)(n0 + srow)      * K_DIM + scol;
    const u16* gb1 = Bg + (size_t)(n0 + 64 + srow) * K_DIM + scol;

    f32x4 acc[4][4];
    #pragma unroll
    for (int m = 0; m < 4; ++m)
        #pragma unroll
        for (int n = 0; n < 4; ++n) acc[m][n] = (f32x4){0.f, 0.f, 0.f, 0.f};

    auto stage = [&](int b, int kt) {
        const int ko = kt * 32;
        char* base = (char*)lds + b * 16384 + wbase;
        GLOAD16(ga0 + ko, base);
        GLOAD16(ga1 + ko, base + 4096);
        GLOAD16(gb0 + ko, base + 8192);
        GLOAD16(gb1 + ko, base + 12288);
    };

    stage(0, 0);
    asm volatile("s_waitcnt vmcnt(0)" ::: "memory");
    __syncthreads();

    for (int kt = 0; kt < 8; ++kt) {
        const int cur = kt & 1;
        if (kt < 7) stage(cur ^ 1, kt + 1);
        const char* la = (const char*)lds + cur * 16384;
        const char* lb = la + 8192;
        bf16x8 af[4], bfr[4];
        #pragma unroll
        for (int m = 0; m < 4; ++m)
            af[m] = *(const bf16x8*)(la + ((wr*64 + m*16 + lr) * 32 + lk * 8) * 2);
        #pragma unroll
        for (int n = 0; n < 4; ++n)
            bfr[n] = *(const bf16x8*)(lb + ((wc*64 + n*16 + lr) * 32 + lk * 8) * 2);
        #pragma unroll
        for (int m = 0; m < 4; ++m)
            #pragma unroll
            for (int n = 0; n < 4; ++n)
                acc[m][n] = __builtin_amdgcn_mfma_f32_16x16x32_bf16(
                    af[m], bfr[n], acc[m][n], 0, 0, 0);
        asm volatile("s_waitcnt vmcnt(0)" ::: "memory");
        __syncthreads();
    }

    float* outn = out + (size_t)z * 256 * L_DIM;
    #pragma unroll
    for (int m = 0; m < 4; ++m) {
        #pragma unroll
        for (int n = 0; n < 4; ++n) {
            const int col = n0 + wc*64 + n*16 + lr;
            #pragma unroll
            for (int r = 0; r < 4; ++r) {
                const int row = m0 + wr*64 + m*16 + lk*4 + r;
                outn[(size_t)row * L_DIM + col] = acc[m][n][r] + pout_b[row];
            }
        }
    }
}

// ---------------------------------------------------------------------------
extern "C" void kernel_launch(void* const* d_in, const int* in_sizes, int n_in,
                              void* d_out, int out_size, void* d_ws, size_t ws_size,
                              hipStream_t stream) {
    const float* x      = (const float*)d_in[0];
    const float* dw_w   = (const float*)d_in[1];
    const float* dw_b   = (const float*)d_in[2];
    const float* pw_w   = (const float*)d_in[3];
    const float* pw_b   = (const float*)d_in[4];
    const float* pin_w  = (const float*)d_in[5];
    const float* pin_b  = (const float*)d_in[6];
    const float* pout_w = (const float*)d_in[7];
    const float* pout_b = (const float*)d_in[8];
    float* out = (float*)d_out;

    char* ws = (char*)d_ws;
    u16*   xb_t    = (u16*)ws;                      //  8,388,608
    u16*   dwc_t   = (u16*)(ws + 8388608);          //  8,388,608
    u16*   val_b   = (u16*)(ws + 16777216);         //  8,388,608
    u16*   acc_b   = (u16*)(ws + 25165824);         //  8,388,608
    float* omb     = (float*)(ws + 33554432);       //  7,340,032
    u16*   pin_wb  = (u16*)(ws + 40894464);         //    131,072
    u16*   pw_wb   = (u16*)(ws + 41025536);         //     65,536 (128 rows)
    u16*   pout_wb = (u16*)(ws + 41091072);         //    131,072

    // K1: depthwise conv + transpose-cast + weight casts
    prep_kernel<<<dim3(5, 64, NBATCH), 256, 0, stream>>>(
        x, dw_w, dw_b, pin_w, pw_w, pout_w,
        xb_t, dwc_t, pin_wb, pw_wb, pout_wb);

    // K2: val = pin(x) [bf16], om = pw(dwc) [fp32]
    gemm_dual<<<dim3(3, 128), 256, 0, stream>>>(
        xb_t, dwc_t, pin_wb, pw_wb, pin_b, pw_b, val_b, omb);

    // K3a: deformable gather at max occupancy
    gather_kernel<<<dim3(2048), 256, 0, stream>>>(omb, val_b, acc_b);

    // K3b: pout GEMM, transposed fp32 output
    gemm_pout<<<dim3(32, 2, NBATCH), 256, 0, stream>>>(
        acc_b, pout_wb, pout_b, out);
}

// Round 15
// 57.464 us; speedup vs baseline: 3.2584x; 1.0203x over previous
//
#include <hip/hip_runtime.h>

typedef unsigned short u16;
typedef short bf16x8 __attribute__((ext_vector_type(8)));
typedef u16 u16x8 __attribute__((ext_vector_type(8)));
typedef float f32x4 __attribute__((ext_vector_type(4)));

#define K_DIM 256
#define L_DIM 4096
#define NBATCH 4

static __device__ __forceinline__ u16 f2bf(float f) {
    unsigned u = __float_as_uint(f);
    unsigned r = (u + 0x7FFFu + ((u >> 16) & 1u)) >> 16;
    return (u16)r;
}
static __device__ __forceinline__ float bf2f(u16 v) {
    return __uint_as_float(((unsigned)v) << 16);
}

#define GLOAD16(g, l) __builtin_amdgcn_global_load_lds( \
    (const __attribute__((address_space(1))) void*)(g), \
    (__attribute__((address_space(3))) void*)(l), 16, 0, 0)

// ---------------------------------------------------------------------------
// K1: depthwise 3x3 conv + transpose + bf16 cast; weight casts folded in.
// [R14 verbatim]
// ---------------------------------------------------------------------------
__global__ __launch_bounds__(256) void prep_kernel(
    const float* __restrict__ x, const float* __restrict__ dw_w,
    const float* __restrict__ dw_b, const float* __restrict__ pin_w,
    const float* __restrict__ pw_w, const float* __restrict__ pout_w,
    u16* __restrict__ xb_t, u16* __restrict__ dwc_t,
    u16* __restrict__ pin_wb, u16* __restrict__ pw_wb,
    u16* __restrict__ pout_wb)
{
    if (blockIdx.x == 4) {                      // weight-cast blocks
        if (blockIdx.z != 0) return;
        const int end = (blockIdx.y + 1) * 2560;
        for (int k = blockIdx.y * 2560 + threadIdx.x; k < end; k += 256) {
            if (k < 65536) pin_wb[k] = f2bf(pin_w[k]);
            else if (k < 98304) {
                int j = k - 65536;
                pw_wb[j] = ((j >> 8) < 112) ? f2bf(pw_w[j]) : (u16)0;
            } else {
                int j = k - 98304;
                pout_wb[j] = f2bf(pout_w[j]);
            }
        }
        return;
    }

    __shared__ u16 tx_[64][66];
    __shared__ u16 td_[64][66];
    const int c0 = blockIdx.x * 64, h = blockIdx.y, n = blockIdx.z;
    const int t = threadIdx.x;
    const float* xn = x + (size_t)n * 256 * L_DIM;

    const int w4 = (t & 15) * 4;          // 0..60
    const int cs = t >> 4;                // 0..15

    #pragma unroll
    for (int j = 0; j < 4; ++j) {
        const int cl = cs * 4 + j, c = c0 + cl;
        const float* xc = xn + (size_t)c * L_DIM;
        const float* w9 = dw_w + c * 9;

        float s[4];
        const float bv = dw_b[c];
        #pragma unroll
        for (int k = 0; k < 4; ++k) s[k] = bv;
        f32x4 center;

        #pragma unroll
        for (int dy = 0; dy < 3; ++dy) {
            const int hh = h + dy - 1;
            if (hh < 0 || hh > 63) continue;        // block-uniform
            const float* row = xc + hh * 64;
            const f32x4 m = *(const f32x4*)(row + w4);
            const float flv = row[(w4 > 0) ? w4 - 1 : 0];
            const float frv = row[(w4 + 4 < 64) ? w4 + 4 : 63];
            if (dy == 1) center = m;
            #pragma unroll
            for (int k = 0; k < 4; ++k) {
                const int w = w4 + k;
                const float lv = (w > 0) ? 1.f : 0.f;
                const float rv = (w < 63) ? 1.f : 0.f;
                const float xm = (k == 0) ? flv : m[k - 1];
                const float xp = (k == 3) ? frv : m[k + 1];
                s[k] = fmaf(xm * lv, w9[dy*3 + 0], s[k]);
                s[k] = fmaf(m[k],    w9[dy*3 + 1], s[k]);
                s[k] = fmaf(xp * rv, w9[dy*3 + 2], s[k]);
            }
        }
        #pragma unroll
        for (int k = 0; k < 4; ++k) {
            tx_[w4 + k][cl] = f2bf(center[k]);
            td_[w4 + k][cl] = f2bf(s[k]);
        }
    }
    __syncthreads();

    const int cc = t & 63, cq = t >> 6;
    for (int j = 0; j < 16; ++j) {
        const int wl = j * 4 + cq;
        const size_t o = ((size_t)n * L_DIM + h * 64 + wl) * 256 + c0 + cc;
        xb_t[o]  = tx_[wl][cc];
        dwc_t[o] = td_[wl][cc];
    }
}

// ---------------------------------------------------------------------------
// K2: pin + pw GEMMs in one dispatch.   [R14 verbatim]
// ---------------------------------------------------------------------------
__global__ __launch_bounds__(256) void gemm_dual(
    const u16* __restrict__ xb_t, const u16* __restrict__ dwc_t,
    const u16* __restrict__ pin_wb, const u16* __restrict__ pw_wb,
    const float* __restrict__ pin_b, const float* __restrict__ pw_b,
    u16* __restrict__ val_b, float* __restrict__ omb)
{
    __shared__ u16 lds[16384];
    const int bx = blockIdx.x;
    const bool isPw = (bx == 2);
    const u16* Ag = isPw ? dwc_t : xb_t;
    const u16* Bg = isPw ? pw_wb : pin_wb;
    const float* bias = isPw ? pw_b : pin_b;
    const int n0 = isPw ? 0 : bx * 128;
    const int Ncols = isPw ? 112 : 256;
    const int ldC = isPw ? 112 : 256;
    const int m0 = blockIdx.y * 128;

    const int t = threadIdx.x;
    const int wave = t >> 6, lane = t & 63;
    const int lr = lane & 15, lk = lane >> 4;
    const int wr = wave >> 1, wc = wave & 1;
    const int wbase = wave << 10;

    const int srow = t >> 2;
    const int scol = (t & 3) * 8;
    const u16* ga0 = Ag + (size_t)(m0 + srow)      * K_DIM + scol;
    const u16* ga1 = Ag + (size_t)(m0 + 64 + srow) * K_DIM + scol;
    const u16* gb0 = Bg + (size_t)(n0 + srow)      * K_DIM + scol;
    const u16* gb1 = Bg + (size_t)(n0 + 64 + srow) * K_DIM + scol;

    f32x4 acc[4][4];
    #pragma unroll
    for (int m = 0; m < 4; ++m)
        #pragma unroll
        for (int n = 0; n < 4; ++n) acc[m][n] = (f32x4){0.f, 0.f, 0.f, 0.f};

    auto stage = [&](int b, int kt) {
        const int ko = kt * 32;
        char* base = (char*)lds + b * 16384 + wbase;
        GLOAD16(ga0 + ko, base);
        GLOAD16(ga1 + ko, base + 4096);
        GLOAD16(gb0 + ko, base + 8192);
        GLOAD16(gb1 + ko, base + 12288);
    };

    stage(0, 0);
    asm volatile("s_waitcnt vmcnt(0)" ::: "memory");
    __syncthreads();

    for (int kt = 0; kt < 8; ++kt) {
        const int cur = kt & 1;
        if (kt < 7) stage(cur ^ 1, kt + 1);
        const char* la = (const char*)lds + cur * 16384;
        const char* lb = la + 8192;
        bf16x8 af[4], bfr[4];
        #pragma unroll
        for (int m = 0; m < 4; ++m)
            af[m] = *(const bf16x8*)(la + ((wr*64 + m*16 + lr) * 32 + lk * 8) * 2);
        #pragma unroll
        for (int n = 0; n < 4; ++n)
            bfr[n] = *(const bf16x8*)(lb + ((wc*64 + n*16 + lr) * 32 + lk * 8) * 2);
        #pragma unroll
        for (int m = 0; m < 4; ++m)
            #pragma unroll
            for (int n = 0; n < 4; ++n)
                acc[m][n] = __builtin_amdgcn_mfma_f32_16x16x32_bf16(
                    af[m], bfr[n], acc[m][n], 0, 0, 0);
        asm volatile("s_waitcnt vmcnt(0)" ::: "memory");
        __syncthreads();
    }

    #pragma unroll
    for (int m = 0; m < 4; ++m) {
        #pragma unroll
        for (int n = 0; n < 4; ++n) {
            const int col = n0 + wc*64 + n*16 + lr;
            if (col < Ncols) {
                const float bv = bias[col];
                #pragma unroll
                for (int r = 0; r < 4; ++r) {
                    const int row = m0 + wr*64 + m*16 + lk*4 + r;
                    const float o = acc[m][n][r] + bv;
                    const size_t off = (size_t)row * ldC + col;
                    if (isPw) omb[off] = o;
                    else      val_b[off] = f2bf(o);
                }
            }
        }
    }
}

// ---------------------------------------------------------------------------
// K3a: deformable bilinear gather.  [R14 base]
// TWO CHANGES: __launch_bounds__(256,8) -> (256,4) (VGPR cap 64 -> 128, so
// the compiler can batch more loads in flight per wave; R14's 64-cap forced
// serialization that cancelled its occupancy gain), and full unroll of the
// p-loop (address CSE across taps + global load scheduling).
// ---------------------------------------------------------------------------
__global__ __launch_bounds__(256, 4) void gather_kernel(
    const float* __restrict__ om, const u16* __restrict__ val,
    u16* __restrict__ accb)
{
    __shared__ float som[904];                 // 8*112 floats + pad
    const int blk = blockIdx.x;                // 0..2047
    const int grp = (blk & 7) * 256 + (blk >> 3);   // pos-group 0..2047
    const int n = grp >> 9;                    // 512 groups per n
    const int l0 = (grp & 511) * 8;            // 8-pos base within n
    const int t = threadIdx.x;

    // stage om slice (3584 B): waves 0-2 full, wave 3 lanes 0-31
    {
        const float* omsrc = om + ((size_t)n * L_DIM + l0) * 112;
        if (t < 224) {
            const int wb = (t >> 6) << 10;     // wave-uniform byte base
            GLOAD16(omsrc + t * 4, (char*)som + wb);
        }
        asm volatile("s_waitcnt vmcnt(0)" ::: "memory");
        __syncthreads();
    }

    const int pos = t >> 5;                    // 0..7
    const int g = (t >> 3) & 3;
    const int ch = (t & 7) * 8;
    const int l = l0 + pos;
    const float* omp = som + pos * 112 + g * 27;
    const u16* vb = val + (size_t)n * L_DIM * 256 + g * 64 + ch;
    const float ybase = (float)(l >> 6) - 1.f;
    const float xb = (float)(l & 63) - 1.f;

    float a[8];
    #pragma unroll
    for (int j = 0; j < 8; ++j) a[j] = 0.f;

    #pragma unroll
    for (int p = 0; p < 9; ++p) {
        const float ox = omp[p*3 + 0];
        const float oy = omp[p*3 + 1];
        const float mk = omp[p*3 + 2];
        const float py = ybase + (float)(p / 3) + oy;
        const float px = xb + (float)(p % 3) + ox;
        const float y0 = floorf(py), x0 = floorf(px);
        const float fy = py - y0, fx = px - x0;
        const int iy0 = (int)y0, ix0 = (int)x0;
        const float wy[2] = {mk * (1.f - fy), mk * fy};
        const float wx[2] = {1.f - fx, fx};
        #pragma unroll
        for (int c4 = 0; c4 < 4; ++c4) {
            const int dy = c4 >> 1, dx = c4 & 1;
            const int iy = iy0 + dy, ix = ix0 + dx;
            const bool ok = ((unsigned)iy < 64u) & ((unsigned)ix < 64u);
            const float wgt = ok ? wy[dy] * wx[dx] : 0.f;
            const int iyc = min(max(iy, 0), 63);
            const int ixc = min(max(ix, 0), 63);
            const u16x8 v = *(const u16x8*)(vb + (size_t)(iyc * 64 + ixc) * 256);
            #pragma unroll
            for (int j = 0; j < 8; ++j) a[j] = fmaf(wgt, bf2f(v[j]), a[j]);
        }
    }
    u16x8 o;
    #pragma unroll
    for (int j = 0; j < 8; ++j) o[j] = f2bf(a[j]);
    *(u16x8*)(accb + ((size_t)n * L_DIM + l) * 256 + g * 64 + ch) = o;
}

// ---------------------------------------------------------------------------
// K3b: pout GEMM.  [R14 verbatim]
// ---------------------------------------------------------------------------
__global__ __launch_bounds__(256) void gemm_pout(
    const u16* __restrict__ accb, const u16* __restrict__ pout_wb,
    const float* __restrict__ pout_b, float* __restrict__ out)
{
    __shared__ u16 lds[16384];
    const int z = blockIdx.z;
    const u16* Bg = accb + (size_t)z * L_DIM * 256;
    const int n0 = blockIdx.x * 128;           // l tile
    const int m0 = blockIdx.y * 128;           // c tile

    const int t = threadIdx.x;
    const int wave = t >> 6, lane = t & 63;
    const int lr = lane & 15, lk = lane >> 4;
    const int wr = wave >> 1, wc = wave & 1;
    const int wbase = wave << 10;

    const int srow = t >> 2;
    const int scol = (t & 3) * 8;
    const u16* ga0 = pout_wb + (size_t)(m0 + srow)      * K_DIM + scol;
    const u16* ga1 = pout_wb + (size_t)(m0 + 64 + srow) * K_DIM + scol;
    const u16* gb0 = Bg + (size_t)(n0 + srow)      * K_DIM + scol;
    const u16* gb1 = Bg + (size_t)(n0 + 64 + srow) * K_DIM + scol;

    f32x4 acc[4][4];
    #pragma unroll
    for (int m = 0; m < 4; ++m)
        #pragma unroll
        for (int n = 0; n < 4; ++n) acc[m][n] = (f32x4){0.f, 0.f, 0.f, 0.f};

    auto stage = [&](int b, int kt) {
        const int ko = kt * 32;
        char* base = (char*)lds + b * 16384 + wbase;
        GLOAD16(ga0 + ko, base);
        GLOAD16(ga1 + ko, base + 4096);
        GLOAD16(gb0 + ko, base + 8192);
        GLOAD16(gb1 + ko, base + 12288);
    };

    stage(0, 0);
    asm volatile("s_waitcnt vmcnt(0)" ::: "memory");
    __syncthreads();

    for (int kt = 0; kt < 8; ++kt) {
        const int cur = kt & 1;
        if (kt < 7) stage(cur ^ 1, kt + 1);
        const char* la = (const char*)lds + cur * 16384;
        const char* lb = la + 8192;
        bf16x8 af[4], bfr[4];
        #pragma unroll
        for (int m = 0; m < 4; ++m)
            af[m] = *(const bf16x8*)(la + ((wr*64 + m*16 + lr) * 32 + lk * 8) * 2);
        #pragma unroll
        for (int n = 0; n < 4; ++n)
            bfr[n] = *(const bf16x8*)(lb + ((wc*64 + n*16 + lr) * 32 + lk * 8) * 2);
        #pragma unroll
        for (int m = 0; m < 4; ++m)
            #pragma unroll
            for (int n = 0; n < 4; ++n)
                acc[m][n] = __builtin_amdgcn_mfma_f32_16x16x32_bf16(
                    af[m], bfr[n], acc[m][n], 0, 0, 0);
        asm volatile("s_waitcnt vmcnt(0)" ::: "memory");
        __syncthreads();
    }

    float* outn = out + (size_t)z * 256 * L_DIM;
    #pragma unroll
    for (int m = 0; m < 4; ++m) {
        #pragma unroll
        for (int n = 0; n < 4; ++n) {
            const int col = n0 + wc*64 + n*16 + lr;
            #pragma unroll
            for (int r = 0; r < 4; ++r) {
                const int row = m0 + wr*64 + m*16 + lk*4 + r;
                outn[(size_t)row * L_DIM + col] = acc[m][n][r] + pout_b[row];
            }
        }
    }
}

// ---------------------------------------------------------------------------
extern "C" void kernel_launch(void* const* d_in, const int* in_sizes, int n_in,
                              void* d_out, int out_size, void* d_ws, size_t ws_size,
                              hipStream_t stream) {
    const float* x      = (const float*)d_in[0];
    const float* dw_w   = (const float*)d_in[1];
    const float* dw_b   = (const float*)d_in[2];
    const float* pw_w   = (const float*)d_in[3];
    const float* pw_b   = (const float*)d_in[4];
    const float* pin_w  = (const float*)d_in[5];
    const float* pin_b  = (const float*)d_in[6];
    const float* pout_w = (const float*)d_in[7];
    const float* pout_b = (const float*)d_in[8];
    float* out = (float*)d_out;

    char* ws = (char*)d_ws;
    u16*   xb_t    = (u16*)ws;                      //  8,388,608
    u16*   dwc_t   = (u16*)(ws + 8388608);          //  8,388,608
    u16*   val_b   = (u16*)(ws + 16777216);         //  8,388,608
    u16*   acc_b   = (u16*)(ws + 25165824);         //  8,388,608
    float* omb     = (float*)(ws + 33554432);       //  7,340,032
    u16*   pin_wb  = (u16*)(ws + 40894464);         //    131,072
    u16*   pw_wb   = (u16*)(ws + 41025536);         //     65,536 (128 rows)
    u16*   pout_wb = (u16*)(ws + 41091072);         //    131,072

    // K1: depthwise conv + transpose-cast + weight casts
    prep_kernel<<<dim3(5, 64, NBATCH), 256, 0, stream>>>(
        x, dw_w, dw_b, pin_w, pw_w, pout_w,
        xb_t, dwc_t, pin_wb, pw_wb, pout_wb);

    // K2: val = pin(x) [bf16], om = pw(dwc) [fp32]
    gemm_dual<<<dim3(3, 128), 256, 0, stream>>>(
        xb_t, dwc_t, pin_wb, pw_wb, pin_b, pw_b, val_b, omb);

    // K3a: deformable gather, 128-VGPR budget + full unroll
    gather_kernel<<<dim3(2048), 256, 0, stream>>>(omb, val_b, acc_b);

    // K3b: pout GEMM, transposed fp32 output
    gemm_pout<<<dim3(32, 2, NBATCH), 256, 0, stream>>>(
        acc_b, pout_wb, pout_b, out);
}